// Round 7
// baseline (149.710 us; speedup 1.0000x reference)
//
#include <hip/hip_runtime.h>
#include <hip/hip_bf16.h>

#define NN 384
#define HH 768
#define HP 772   // padded LDS row (772%8==4 -> row bases spread over banks, 16B aligned)
#define L2E 1.4426950408889634f
#define TWO_L2E 2.8853900817779268f
#define INV_SQRT_H 0.03608439182435161f

__device__ __forceinline__ float exp2_hw(float x) { return __builtin_amdgcn_exp2f(x); }
__device__ __forceinline__ float rcp_hw(float x) { return __builtin_amdgcn_rcpf(x); }

// ---------------- K1: att[i][j] = sum_k tanh(x_i[k]*y_j[k]) / sqrt(H) ----------------
// Lane-per-output, 4 independent accumulator chains, no shuffles in hot loop.
// Also writes attT (transposed) so every k_tail read is coalesced, and zeroes the
// grid-barrier area (block (0,0)) so each graph replay gets fresh barrier state.
__global__ __launch_bounds__(256) void k_att(const float* __restrict__ X,
                                             const float* __restrict__ Y,
                                             float* __restrict__ att,
                                             float* __restrict__ attT,
                                             unsigned* __restrict__ bar) {
    __shared__ float xs[8 * HP];
    __shared__ float ys[8 * HP];
    __shared__ float part[4][64];
    const int tid = threadIdx.x;
    const int i0 = blockIdx.y * 8, j0 = blockIdx.x * 8;

    if (blockIdx.x == 0 && blockIdx.y == 0) bar[tid] = 0u;  // 256 u32 = 1KB barrier area

    const float4* gx = (const float4*)(X + i0 * HH);
    const float4* gy = (const float4*)(Y + j0 * HH);
#pragma unroll
    for (int p = 0; p < 6; p++) {
        int e = tid + p * 256;
        int r = e / 192, c = e - r * 192;
        float4 vx = gx[e];
        float4 vy = gy[e];
        ((float4*)(xs + r * HP))[c] = vx;
        vy.x *= TWO_L2E; vy.y *= TWO_L2E; vy.z *= TWO_L2E; vy.w *= TWO_L2E;
        ((float4*)(ys + r * HP))[c] = vy;
    }
    __syncthreads();

    const int wv = tid >> 6, ln = tid & 63;
    const int i = ln >> 3, j = ln & 7;
    const float4* xr = (const float4*)(xs + i * HP) + wv * 48;
    const float4* yr = (const float4*)(ys + j * HP) + wv * 48;
    float a0 = 0.f, a1 = 0.f, a2 = 0.f, a3 = 0.f;
#pragma unroll 8
    for (int m = 0; m < 48; m++) {
        float4 a = xr[m];
        float4 b = yr[m];
        a0 += rcp_hw(exp2_hw(a.x * b.x) + 1.f);
        a1 += rcp_hw(exp2_hw(a.y * b.y) + 1.f);
        a2 += rcp_hw(exp2_hw(a.z * b.z) + 1.f);
        a3 += rcp_hw(exp2_hw(a.w * b.w) + 1.f);
    }
    part[wv][ln] = (a0 + a1) + (a2 + a3);
    __syncthreads();
    if (tid < 64) {
        float s = part[0][tid] + part[1][tid] + part[2][tid] + part[3][tid];
        int ii = tid >> 3, jj = tid & 7;
        float v = (768.f - 2.f * s) * INV_SQRT_H;
        att[(i0 + ii) * NN + (j0 + jj)] = v;
        attT[(j0 + jj) * NN + (i0 + ii)] = v;
    }
}

// ---------------- block-wide reductions (256 threads) ----------------
__device__ __forceinline__ float blk_sum(float v, float* tmp) {
#pragma unroll
    for (int o = 32; o; o >>= 1) v += __shfl_xor(v, o, 64);
    int t = threadIdx.x;
    if ((t & 63) == 0) tmp[t >> 6] = v;
    __syncthreads();
    float r = (tmp[0] + tmp[1]) + (tmp[2] + tmp[3]);
    __syncthreads();
    return r;
}
__device__ __forceinline__ float blk_max(float v, float* tmp) {
#pragma unroll
    for (int o = 32; o; o >>= 1) v = fmaxf(v, __shfl_xor(v, o, 64));
    int t = threadIdx.x;
    if ((t & 63) == 0) tmp[t >> 6] = v;
    __syncthreads();
    float r = fmaxf(fmaxf(tmp[0], tmp[1]), fmaxf(tmp[2], tmp[3]));
    __syncthreads();
    return r;
}

// ---------------- grid barrier (all blocks co-resident; device-scope atomics) ----
// Per-XCD L2s are not coherent: spin uses atomic RMW (coherent point), with
// __threadfence release/acquire around arrival/wakeup.
__device__ __forceinline__ void grid_bar(unsigned* bar, int idx, unsigned nb) {
    __syncthreads();
    if (threadIdx.x == 0) {
        unsigned* cnt = bar + idx * 64;
        unsigned* flg = cnt + 32;
        __threadfence();
        unsigned old = atomicAdd(cnt, 1u);
        if (old == nb - 1u) {
            atomicExch(flg, 1u);
        } else {
            while (atomicAdd(flg, 0u) == 0u) { __builtin_amdgcn_s_sleep(2); }
        }
        __threadfence();
    }
    __syncthreads();
}

// ---------------- K2: fused tail — stats, typ, w, proto, cls ----------------
__global__ __launch_bounds__(256) void k_tail(const float* __restrict__ att,
                                              const float* __restrict__ attT,
                                              const float* __restrict__ X,
                                              const float* __restrict__ Y,
                                              const float* __restrict__ W,
                                              const float* __restrict__ bias,
                                              float* rowM, float* rowRS, float* colM, float* colRS,
                                              float* hyper_typ, float* hypo_typ,
                                              float* w_hyper, float* w_hypo,
                                              float* hp, float* hq,
                                              unsigned* bar, float* out) {
    __shared__ float tmp[4];
    __shared__ float red[4][64];
    const int b = blockIdx.x, t = threadIdx.x;
    const unsigned nb = gridDim.x;

    // ---- Phase A: row b and col b softmax stats (max + reciprocal expsum) ----
    {
        float a0 = att[b * NN + t];
        float a1 = (t < 128) ? att[b * NN + 256 + t] : -1e30f;
        float M = blk_max(fmaxf(a0, a1), tmp);
        float s = exp2_hw((a0 - M) * L2E) + ((t < 128) ? exp2_hw((a1 - M) * L2E) : 0.f);
        float S = blk_sum(s, tmp);
        if (t == 0) { rowM[b] = M; rowRS[b] = 1.f / S; }

        float c0 = attT[b * NN + t];
        float c1 = (t < 128) ? attT[b * NN + 256 + t] : -1e30f;
        float Mc = blk_max(fmaxf(c0, c1), tmp);
        float sc = exp2_hw((c0 - Mc) * L2E) + ((t < 128) ? exp2_hw((c1 - Mc) * L2E) : 0.f);
        float Sc = blk_sum(sc, tmp);
        if (t == 0) { colM[b] = Mc; colRS[b] = 1.f / Sc; }
    }
    grid_bar(bar, 0, nb);

    // ---- Phase B: typicalness ----
    // hyper_typ[b] = (1/N) sum_i Prow[i][b] ; hypo_typ[b] = (1/N) sum_j Pcol[b][j]
    {
        float s1 = 0.f, s2 = 0.f;
        for (int i = t; i < NN; i += 256) s1 += exp2_hw((attT[b * NN + i] - rowM[i]) * L2E) * rowRS[i];
        for (int j = t; j < NN; j += 256) s2 += exp2_hw((att[b * NN + j] - colM[j]) * L2E) * colRS[j];
        float S1 = blk_sum(s1, tmp);
        float S2 = blk_sum(s2, tmp);
        if (t == 0) { hyper_typ[b] = S1 * (1.f / NN); hypo_typ[b] = S2 * (1.f / NN); }
    }
    grid_bar(bar, 1, nb);

    // ---- Phase C: attention weights ----
    // w_hyper[b] = sum_i Prow[i][b]*hypo_typ[i] ; w_hypo[b] = sum_j Pcol[b][j]*hyper_typ[j]
    {
        float u1 = 0.f, u2 = 0.f;
        for (int i = t; i < NN; i += 256) u1 += exp2_hw((attT[b * NN + i] - rowM[i]) * L2E) * rowRS[i] * hypo_typ[i];
        for (int j = t; j < NN; j += 256) u2 += exp2_hw((att[b * NN + j] - colM[j]) * L2E) * colRS[j] * hyper_typ[j];
        float U1 = blk_sum(u1, tmp);
        float U2 = blk_sum(u2, tmp);
        if (t == 0) { w_hyper[b] = U1; w_hypo[b] = U2; }
    }
    grid_bar(bar, 2, nb);

    // ---- Phase D: prototypes (blocks 0..23) ----
    if (b < 24) {
        bool hyper = b < 12;
        int bb = hyper ? b : b - 12;
        int dl = t & 63, w = t >> 6;
        int d = bb * 64 + dl;
        float s = 0.f;
        if (hyper) {
            for (int j = w * 96; j < w * 96 + 96; j++) s += w_hyper[j] * Y[j * HH + d];
        } else {
            for (int i = w * 96; i < w * 96 + 96; i++) s += w_hypo[i] * X[i * HH + d];
        }
        red[w][dl] = s;
        __syncthreads();
        if (t < 64) {
            float S = red[0][t] + red[1][t] + red[2][t] + red[3][t];
            if (hyper) hp[bb * 64 + t] = S;
            else       hq[bb * 64 + t] = S;
        }
    }
    grid_bar(bar, 3, nb);

    // ---- Phase E: classifier (block 0) ----
    if (b == 0) {
        float acc0 = 0.f, acc1 = 0.f, acc2 = 0.f;
        for (int d = t; d < 4 * HH; d += 256) {
            int seg = d / HH, r = d - seg * HH;
            float f = (seg == 0) ? hp[r] : (seg == 1) ? hq[r] : (seg == 2) ? (hp[r] - hq[r]) : (hp[r] * hq[r]);
            acc0 += W[d] * f;
            acc1 += W[3072 + d] * f;
            acc2 += W[6144 + d] * f;
        }
        float A0 = blk_sum(acc0, tmp);
        float A1 = blk_sum(acc1, tmp);
        float A2 = blk_sum(acc2, tmp);
        if (t == 0) {
            out[0] = A0 + bias[0];
            out[1] = A1 + bias[1];
            out[2] = A2 + bias[2];
        }
    }
}

extern "C" void kernel_launch(void* const* d_in, const int* in_sizes, int n_in,
                              void* d_out, int out_size, void* d_ws, size_t ws_size,
                              hipStream_t stream) {
    const float* X = (const float*)d_in[0];   // hypo_embeddings [384,768] fp32
    const float* Y = (const float*)d_in[1];   // hyper_embeddings [384,768] fp32
    const float* W = (const float*)d_in[2];   // W_cls [3,3072] fp32
    const float* B = (const float*)d_in[3];   // b_cls [3] fp32
    float* out = (float*)d_out;               // fp32 output

    float* ws = (float*)d_ws;
    float* att       = ws;                  // 147456
    float* attT      = att + NN * NN;       // 147456
    float* rowM      = attT + NN * NN;      // 384
    float* rowRS     = rowM + NN;
    float* colM      = rowRS + NN;
    float* colRS     = colM + NN;
    float* hyper_typ = colRS + NN;
    float* hypo_typ  = hyper_typ + NN;
    float* w_hyper   = hypo_typ + NN;
    float* w_hypo    = w_hyper + NN;
    float* hp        = w_hypo + NN;         // 768
    float* hq        = hp + HH;             // 768
    unsigned* bar    = (unsigned*)(hq + HH); // 256 u32 (4 barriers x 64 u32)

    k_att<<<dim3(48, 48), 256, 0, stream>>>(X, Y, att, attT, bar);
    k_tail<<<384, 256, 0, stream>>>(att, attT, X, Y, W, B,
                                    rowM, rowRS, colM, colRS,
                                    hyper_typ, hypo_typ, w_hyper, w_hypo,
                                    hp, hq, bar, out);
}

// Round 8
// 119.727 us; speedup vs baseline: 1.2504x; 1.2504x over previous
//
#include <hip/hip_runtime.h>
#include <hip/hip_bf16.h>

#define NN 384
#define HH 768
#define HP 772   // padded LDS row (772%8==4 -> row bases spread over banks, 16B aligned)
#define L2E 1.4426950408889634f
#define TWO_L2E 2.8853900817779268f
#define INV_SQRT_H 0.03608439182435161f

__device__ __forceinline__ float exp2_hw(float x) { return __builtin_amdgcn_exp2f(x); }
__device__ __forceinline__ float rcp_hw(float x) { return __builtin_amdgcn_rcpf(x); }

// ---------------- K1: att[i][j] = sum_k tanh(x_i[k]*y_j[k]) / sqrt(H) ----------------
// Lane-per-output, 4 independent accumulator chains, no shuffles in hot loop.
// Writes att and attT (all tail reads coalesced); zeroes barrier area (block (0,0)).
__global__ __launch_bounds__(256) void k_att(const float* __restrict__ X,
                                             const float* __restrict__ Y,
                                             float* __restrict__ att,
                                             float* __restrict__ attT,
                                             unsigned* __restrict__ bar) {
    __shared__ float xs[8 * HP];
    __shared__ float ys[8 * HP];
    __shared__ float part[4][64];
    const int tid = threadIdx.x;
    const int i0 = blockIdx.y * 8, j0 = blockIdx.x * 8;

    if (blockIdx.x == 0 && blockIdx.y == 0) bar[tid] = 0u;  // 4 barriers x 64 u32

    const float4* gx = (const float4*)(X + i0 * HH);
    const float4* gy = (const float4*)(Y + j0 * HH);
#pragma unroll
    for (int p = 0; p < 6; p++) {
        int e = tid + p * 256;
        int r = e / 192, c = e - r * 192;
        float4 vx = gx[e];
        float4 vy = gy[e];
        ((float4*)(xs + r * HP))[c] = vx;
        vy.x *= TWO_L2E; vy.y *= TWO_L2E; vy.z *= TWO_L2E; vy.w *= TWO_L2E;
        ((float4*)(ys + r * HP))[c] = vy;
    }
    __syncthreads();

    const int wv = tid >> 6, ln = tid & 63;
    const int i = ln >> 3, j = ln & 7;
    const float4* xr = (const float4*)(xs + i * HP) + wv * 48;
    const float4* yr = (const float4*)(ys + j * HP) + wv * 48;
    float a0 = 0.f, a1 = 0.f, a2 = 0.f, a3 = 0.f;
#pragma unroll 8
    for (int m = 0; m < 48; m++) {
        float4 a = xr[m];
        float4 b = yr[m];
        a0 += rcp_hw(exp2_hw(a.x * b.x) + 1.f);
        a1 += rcp_hw(exp2_hw(a.y * b.y) + 1.f);
        a2 += rcp_hw(exp2_hw(a.z * b.z) + 1.f);
        a3 += rcp_hw(exp2_hw(a.w * b.w) + 1.f);
    }
    part[wv][ln] = (a0 + a1) + (a2 + a3);
    __syncthreads();
    if (tid < 64) {
        float s = part[0][tid] + part[1][tid] + part[2][tid] + part[3][tid];
        int ii = tid >> 3, jj = tid & 7;
        float v = (768.f - 2.f * s) * INV_SQRT_H;
        att[(i0 + ii) * NN + (j0 + jj)] = v;
        attT[(j0 + jj) * NN + (i0 + ii)] = v;
    }
}

// ---------------- grid barrier: single RMW arrival + LOAD-ONLY spin ----------------
// Round-7 lesson: spinning with atomic RMW from all blocks serializes at the
// coherent point (~17us/barrier). Load-only polls are serviced concurrently.
__device__ __forceinline__ void grid_bar(unsigned* bar, int idx, unsigned nb) {
    __syncthreads();
    if (threadIdx.x == 0) {
        unsigned* cnt = bar + idx * 64;
        unsigned* flg = cnt + 32;
        __threadfence();
        unsigned old = __hip_atomic_fetch_add(cnt, 1u, __ATOMIC_ACQ_REL, __HIP_MEMORY_SCOPE_AGENT);
        if (old == nb - 1u) {
            __hip_atomic_store(flg, 1u, __ATOMIC_RELEASE, __HIP_MEMORY_SCOPE_AGENT);
        } else {
            while (__hip_atomic_load(flg, __ATOMIC_ACQUIRE, __HIP_MEMORY_SCOPE_AGENT) == 0u) {
                __builtin_amdgcn_s_sleep(4);
            }
        }
        __threadfence();
    }
    __syncthreads();
}

// ---------------- K2: fused tail — 64 blocks, wave-per-item phases ----------------
__global__ __launch_bounds__(256) void k_tail(const float* __restrict__ att,
                                              const float* __restrict__ attT,
                                              const float* __restrict__ X,
                                              const float* __restrict__ Y,
                                              const float* __restrict__ W,
                                              const float* __restrict__ bias,
                                              float* rowM, float* rowRS, float* colM, float* colRS,
                                              float* hyper_typ, float* hypo_typ,
                                              float* w_hyper, float* w_hypo,
                                              float* hp, float* hq,
                                              unsigned* bar, float* out) {
    __shared__ float tmp[4];
    __shared__ float red[4][64];
    const int b = blockIdx.x, t = threadIdx.x;
    const unsigned nb = gridDim.x;
    const int wv = t >> 6, ln = t & 63;
    const int gw = (b << 2) + wv;          // global wave id 0..255

    // ---- Phase A: softmax stats. items 0..383 = rows (att), 384..767 = cols (attT) ----
    for (int it = gw; it < 2 * NN; it += 256) {
        const float* base = (it < NN) ? (att + it * NN) : (attT + (it - NN) * NN);
        float v0 = base[ln], v1 = base[ln + 64], v2 = base[ln + 128];
        float v3 = base[ln + 192], v4 = base[ln + 256], v5 = base[ln + 320];
        float m = fmaxf(fmaxf(fmaxf(v0, v1), fmaxf(v2, v3)), fmaxf(v4, v5));
#pragma unroll
        for (int o = 32; o; o >>= 1) m = fmaxf(m, __shfl_xor(m, o, 64));
        float s = exp2_hw((v0 - m) * L2E) + exp2_hw((v1 - m) * L2E) + exp2_hw((v2 - m) * L2E)
                + exp2_hw((v3 - m) * L2E) + exp2_hw((v4 - m) * L2E) + exp2_hw((v5 - m) * L2E);
#pragma unroll
        for (int o = 32; o; o >>= 1) s += __shfl_xor(s, o, 64);
        if (ln == 0) {
            float rs = 1.f / s;
            if (it < NN) { rowM[it] = m; rowRS[it] = rs; }
            else         { colM[it - NN] = m; colRS[it - NN] = rs; }
        }
    }
    grid_bar(bar, 0, nb);

    // ---- Phase B: typicalness. hyper_typ[j] = (1/N) sum_i Prow[i][j]; hypo_typ[i] = (1/N) sum_j Pcol[i][j] ----
    for (int it = gw; it < 2 * NN; it += 256) {
        float s = 0.f;
        if (it < NN) {
            const float* base = attT + it * NN;
#pragma unroll
            for (int k = 0; k < 6; k++) {
                int i = ln + 64 * k;
                s += exp2_hw((base[i] - rowM[i]) * L2E) * rowRS[i];
            }
        } else {
            const float* base = att + (it - NN) * NN;
#pragma unroll
            for (int k = 0; k < 6; k++) {
                int j = ln + 64 * k;
                s += exp2_hw((base[j] - colM[j]) * L2E) * colRS[j];
            }
        }
#pragma unroll
        for (int o = 32; o; o >>= 1) s += __shfl_xor(s, o, 64);
        if (ln == 0) {
            if (it < NN) hyper_typ[it] = s * (1.f / NN);
            else         hypo_typ[it - NN] = s * (1.f / NN);
        }
    }
    grid_bar(bar, 1, nb);

    // ---- Phase C: weights. w_hyper[j] = sum_i Prow[i][j]*hypo_typ[i]; w_hypo[i] = sum_j Pcol[i][j]*hyper_typ[j] ----
    for (int it = gw; it < 2 * NN; it += 256) {
        float s = 0.f;
        if (it < NN) {
            const float* base = attT + it * NN;
#pragma unroll
            for (int k = 0; k < 6; k++) {
                int i = ln + 64 * k;
                s += exp2_hw((base[i] - rowM[i]) * L2E) * rowRS[i] * hypo_typ[i];
            }
        } else {
            const float* base = att + (it - NN) * NN;
#pragma unroll
            for (int k = 0; k < 6; k++) {
                int j = ln + 64 * k;
                s += exp2_hw((base[j] - colM[j]) * L2E) * colRS[j] * hyper_typ[j];
            }
        }
#pragma unroll
        for (int o = 32; o; o >>= 1) s += __shfl_xor(s, o, 64);
        if (ln == 0) {
            if (it < NN) w_hyper[it] = s;
            else         w_hypo[it - NN] = s;
        }
    }
    grid_bar(bar, 2, nb);

    // ---- Phase D: prototypes (blocks 0..23). hp[d]=sum_j w_hyper[j]Y[j][d]; hq[d]=sum_i w_hypo[i]X[i][d] ----
    if (b < 24) {
        bool hyper = b < 12;
        int bb = hyper ? b : b - 12;
        int d = bb * 64 + ln;
        float s = 0.f;
        if (hyper) {
            for (int j = wv * 96; j < wv * 96 + 96; j++) s += w_hyper[j] * Y[j * HH + d];
        } else {
            for (int i = wv * 96; i < wv * 96 + 96; i++) s += w_hypo[i] * X[i * HH + d];
        }
        red[wv][ln] = s;
        __syncthreads();
        if (t < 64) {
            float S = red[0][t] + red[1][t] + red[2][t] + red[3][t];
            if (hyper) hp[bb * 64 + t] = S;
            else       hq[bb * 64 + t] = S;
        }
    }
    grid_bar(bar, 3, nb);

    // ---- Phase E: classifier (block 0) ----
    if (b == 0) {
        float acc0 = 0.f, acc1 = 0.f, acc2 = 0.f;
        for (int d = t; d < 4 * HH; d += 256) {
            int seg = d / HH, r = d - seg * HH;
            float f = (seg == 0) ? hp[r] : (seg == 1) ? hq[r] : (seg == 2) ? (hp[r] - hq[r]) : (hp[r] * hq[r]);
            acc0 += W[d] * f;
            acc1 += W[3072 + d] * f;
            acc2 += W[6144 + d] * f;
        }
#pragma unroll
        for (int o = 32; o; o >>= 1) {
            acc0 += __shfl_xor(acc0, o, 64);
            acc1 += __shfl_xor(acc1, o, 64);
            acc2 += __shfl_xor(acc2, o, 64);
        }
        if ((t & 63) == 0) { red[0][t >> 6] = acc0; red[1][t >> 6] = acc1; red[2][t >> 6] = acc2; }
        __syncthreads();
        if (t < 3) {
            float S = red[t][0] + red[t][1] + red[t][2] + red[t][3] + bias[t];
            out[t] = S;
        }
    }
}

extern "C" void kernel_launch(void* const* d_in, const int* in_sizes, int n_in,
                              void* d_out, int out_size, void* d_ws, size_t ws_size,
                              hipStream_t stream) {
    const float* X = (const float*)d_in[0];   // hypo_embeddings [384,768] fp32
    const float* Y = (const float*)d_in[1];   // hyper_embeddings [384,768] fp32
    const float* W = (const float*)d_in[2];   // W_cls [3,3072] fp32
    const float* B = (const float*)d_in[3];   // b_cls [3] fp32
    float* out = (float*)d_out;               // fp32 output

    float* ws = (float*)d_ws;
    float* att       = ws;                  // 147456
    float* attT      = att + NN * NN;       // 147456
    float* rowM      = attT + NN * NN;      // 384
    float* rowRS     = rowM + NN;
    float* colM      = rowRS + NN;
    float* colRS     = colM + NN;
    float* hyper_typ = colRS + NN;
    float* hypo_typ  = hyper_typ + NN;
    float* w_hyper   = hypo_typ + NN;
    float* w_hypo    = w_hyper + NN;
    float* hp        = w_hypo + NN;         // 768
    float* hq        = hp + HH;             // 768
    unsigned* bar    = (unsigned*)(hq + HH); // 256 u32 (4 barriers x 64 u32)

    k_att<<<dim3(48, 48), 256, 0, stream>>>(X, Y, att, attT, bar);
    k_tail<<<64, 256, 0, stream>>>(att, attT, X, Y, W, B,
                                   rowM, rowRS, colM, colRS,
                                   hyper_typ, hypo_typ, w_hyper, w_hypo,
                                   hp, hq, bar, out);
}

// Round 9
// 104.429 us; speedup vs baseline: 1.4336x; 1.1465x over previous
//
#include <hip/hip_runtime.h>
#include <hip/hip_bf16.h>

#define NN 384
#define HH 768
#define HP 772   // padded LDS row (772%8==4 -> row bases spread over banks, 16B aligned)
#define L2E 1.4426950408889634f
#define TWO_L2E 2.8853900817779268f
#define INV_SQRT_H 0.03608439182435161f

__device__ __forceinline__ float exp2_hw(float x) { return __builtin_amdgcn_exp2f(x); }
__device__ __forceinline__ float rcp_hw(float x) { return __builtin_amdgcn_rcpf(x); }

// Cache-bypassing (write-through / coherent-point) accessors for cross-phase data.
// Relaxed agent-scope atomics: no buffer_inv / buffer_wbl2 cache maintenance.
__device__ __forceinline__ float ld_nc(const float* p) {
    return __hip_atomic_load(p, __ATOMIC_RELAXED, __HIP_MEMORY_SCOPE_AGENT);
}
__device__ __forceinline__ void st_nc(float* p, float v) {
    __hip_atomic_store(p, v, __ATOMIC_RELAXED, __HIP_MEMORY_SCOPE_AGENT);
}

// ---------------- K1: att[i][j] = sum_k tanh(x_i[k]*y_j[k]) / sqrt(H) ----------------
// Lane-per-output, 4 independent accumulator chains, no shuffles in hot loop.
// Writes att and attT (all tail reads coalesced); zeroes barrier area (block (0,0)).
__global__ __launch_bounds__(256) void k_att(const float* __restrict__ X,
                                             const float* __restrict__ Y,
                                             float* __restrict__ att,
                                             float* __restrict__ attT,
                                             unsigned* __restrict__ bar) {
    __shared__ float xs[8 * HP];
    __shared__ float ys[8 * HP];
    __shared__ float part[4][64];
    const int tid = threadIdx.x;
    const int i0 = blockIdx.y * 8, j0 = blockIdx.x * 8;

    if (blockIdx.x == 0 && blockIdx.y == 0) bar[tid] = 0u;  // 4 barriers x 64 u32

    const float4* gx = (const float4*)(X + i0 * HH);
    const float4* gy = (const float4*)(Y + j0 * HH);
#pragma unroll
    for (int p = 0; p < 6; p++) {
        int e = tid + p * 256;
        int r = e / 192, c = e - r * 192;
        float4 vx = gx[e];
        float4 vy = gy[e];
        ((float4*)(xs + r * HP))[c] = vx;
        vy.x *= TWO_L2E; vy.y *= TWO_L2E; vy.z *= TWO_L2E; vy.w *= TWO_L2E;
        ((float4*)(ys + r * HP))[c] = vy;
    }
    __syncthreads();

    const int wv = tid >> 6, ln = tid & 63;
    const int i = ln >> 3, j = ln & 7;
    const float4* xr = (const float4*)(xs + i * HP) + wv * 48;
    const float4* yr = (const float4*)(ys + j * HP) + wv * 48;
    float a0 = 0.f, a1 = 0.f, a2 = 0.f, a3 = 0.f;
#pragma unroll 8
    for (int m = 0; m < 48; m++) {
        float4 a = xr[m];
        float4 b = yr[m];
        a0 += rcp_hw(exp2_hw(a.x * b.x) + 1.f);
        a1 += rcp_hw(exp2_hw(a.y * b.y) + 1.f);
        a2 += rcp_hw(exp2_hw(a.z * b.z) + 1.f);
        a3 += rcp_hw(exp2_hw(a.w * b.w) + 1.f);
    }
    part[wv][ln] = (a0 + a1) + (a2 + a3);
    __syncthreads();
    if (tid < 64) {
        float s = part[0][tid] + part[1][tid] + part[2][tid] + part[3][tid];
        int ii = tid >> 3, jj = tid & 7;
        float v = (768.f - 2.f * s) * INV_SQRT_H;
        att[(i0 + ii) * NN + (j0 + jj)] = v;
        attT[(j0 + jj) * NN + (i0 + ii)] = v;
    }
}

// ---------------- grid barrier: relaxed arrival + relaxed load-only spin ----------
// No acquire/release cache ops (round-8 lesson: acquire spin = buffer_inv storm,
// ACQ_REL arrival = per-block L2 writeback). Ordering argument: __syncthreads()
// drains vmcnt(0) before s_barrier, so a block's write-through data stores are
// globally visible before its thread-0 arrival RMW; the releaser's fetch_add
// returning nb-1 transitively orders all blocks' data; readers use bypass loads.
__device__ __forceinline__ void grid_bar(unsigned* bar, int idx, unsigned nb) {
    __syncthreads();
    if (threadIdx.x == 0) {
        unsigned* cnt = bar + idx * 64;
        unsigned* flg = cnt + 32;
        unsigned old = __hip_atomic_fetch_add(cnt, 1u, __ATOMIC_RELAXED, __HIP_MEMORY_SCOPE_AGENT);
        if (old == nb - 1u) {
            __hip_atomic_store(flg, 1u, __ATOMIC_RELAXED, __HIP_MEMORY_SCOPE_AGENT);
        } else {
            while (__hip_atomic_load(flg, __ATOMIC_RELAXED, __HIP_MEMORY_SCOPE_AGENT) == 0u) {
                __builtin_amdgcn_s_sleep(1);
            }
        }
    }
    __syncthreads();
}

// ---------------- K2: fused tail — 128 blocks, wave-per-item phases ----------------
__global__ __launch_bounds__(256) void k_tail(const float* __restrict__ att,
                                              const float* __restrict__ attT,
                                              const float* __restrict__ X,
                                              const float* __restrict__ Y,
                                              const float* __restrict__ W,
                                              const float* __restrict__ bias,
                                              float* rowM, float* rowRS, float* colM, float* colRS,
                                              float* hyper_typ, float* hypo_typ,
                                              float* w_hyper, float* w_hypo,
                                              float* hp, float* hq,
                                              unsigned* bar, float* out) {
    __shared__ float red[4][64];
    const int b = blockIdx.x, t = threadIdx.x;
    const unsigned nb = gridDim.x;
    const int wv = t >> 6, ln = t & 63;
    const int gw = (b << 2) + wv;          // global wave id 0..511
    const int nw = nb << 2;

    // ---- Phase A: softmax stats. items 0..383 = rows (att), 384..767 = cols (attT) ----
    for (int it = gw; it < 2 * NN; it += nw) {
        const float* base = (it < NN) ? (att + it * NN) : (attT + (it - NN) * NN);
        float v0 = base[ln], v1 = base[ln + 64], v2 = base[ln + 128];
        float v3 = base[ln + 192], v4 = base[ln + 256], v5 = base[ln + 320];
        float m = fmaxf(fmaxf(fmaxf(v0, v1), fmaxf(v2, v3)), fmaxf(v4, v5));
#pragma unroll
        for (int o = 32; o; o >>= 1) m = fmaxf(m, __shfl_xor(m, o, 64));
        float s = exp2_hw((v0 - m) * L2E) + exp2_hw((v1 - m) * L2E) + exp2_hw((v2 - m) * L2E)
                + exp2_hw((v3 - m) * L2E) + exp2_hw((v4 - m) * L2E) + exp2_hw((v5 - m) * L2E);
#pragma unroll
        for (int o = 32; o; o >>= 1) s += __shfl_xor(s, o, 64);
        if (ln == 0) {
            float rs = 1.f / s;
            if (it < NN) { st_nc(rowM + it, m); st_nc(rowRS + it, rs); }
            else         { st_nc(colM + it - NN, m); st_nc(colRS + it - NN, rs); }
        }
    }
    grid_bar(bar, 0, nb);

    // ---- Phase B: typicalness. hyper_typ[j] = (1/N) sum_i Prow[i][j]; hypo_typ[i] = (1/N) sum_j Pcol[i][j] ----
    for (int it = gw; it < 2 * NN; it += nw) {
        float s = 0.f;
        if (it < NN) {
            const float* base = attT + it * NN;
#pragma unroll
            for (int k = 0; k < 6; k++) {
                int i = ln + 64 * k;
                s += exp2_hw((base[i] - ld_nc(rowM + i)) * L2E) * ld_nc(rowRS + i);
            }
        } else {
            const float* base = att + (it - NN) * NN;
#pragma unroll
            for (int k = 0; k < 6; k++) {
                int j = ln + 64 * k;
                s += exp2_hw((base[j] - ld_nc(colM + j)) * L2E) * ld_nc(colRS + j);
            }
        }
#pragma unroll
        for (int o = 32; o; o >>= 1) s += __shfl_xor(s, o, 64);
        if (ln == 0) {
            if (it < NN) st_nc(hyper_typ + it, s * (1.f / NN));
            else         st_nc(hypo_typ + it - NN, s * (1.f / NN));
        }
    }
    grid_bar(bar, 1, nb);

    // ---- Phase C: weights. w_hyper[j] = sum_i Prow[i][j]*hypo_typ[i]; w_hypo[i] = sum_j Pcol[i][j]*hyper_typ[j] ----
    for (int it = gw; it < 2 * NN; it += nw) {
        float s = 0.f;
        if (it < NN) {
            const float* base = attT + it * NN;
#pragma unroll
            for (int k = 0; k < 6; k++) {
                int i = ln + 64 * k;
                s += exp2_hw((base[i] - ld_nc(rowM + i)) * L2E) * ld_nc(rowRS + i) * ld_nc(hypo_typ + i);
            }
        } else {
            const float* base = att + (it - NN) * NN;
#pragma unroll
            for (int k = 0; k < 6; k++) {
                int j = ln + 64 * k;
                s += exp2_hw((base[j] - ld_nc(colM + j)) * L2E) * ld_nc(colRS + j) * ld_nc(hyper_typ + j);
            }
        }
#pragma unroll
        for (int o = 32; o; o >>= 1) s += __shfl_xor(s, o, 64);
        if (ln == 0) {
            if (it < NN) st_nc(w_hyper + it, s);
            else         st_nc(w_hypo + it - NN, s);
        }
    }
    grid_bar(bar, 2, nb);

    // ---- Phase D: prototypes (blocks 0..23). hp[d]=sum_j w_hyper[j]Y[j][d]; hq[d]=sum_i w_hypo[i]X[i][d] ----
    if (b < 24) {
        bool hyper = b < 12;
        int bb = hyper ? b : b - 12;
        int d = bb * 64 + ln;
        float s = 0.f;
        if (hyper) {
            for (int j = wv * 96; j < wv * 96 + 96; j++) s += ld_nc(w_hyper + j) * Y[j * HH + d];
        } else {
            for (int i = wv * 96; i < wv * 96 + 96; i++) s += ld_nc(w_hypo + i) * X[i * HH + d];
        }
        red[wv][ln] = s;
        __syncthreads();
        if (t < 64) {
            float S = red[0][t] + red[1][t] + red[2][t] + red[3][t];
            if (hyper) st_nc(hp + bb * 64 + t, S);
            else       st_nc(hq + bb * 64 + t, S);
        }
    }
    grid_bar(bar, 3, nb);

    // ---- Phase E: classifier (block 0) ----
    if (b == 0) {
        float acc0 = 0.f, acc1 = 0.f, acc2 = 0.f;
        for (int d = t; d < 4 * HH; d += 256) {
            int seg = d / HH, r = d - seg * HH;
            float hpv = ld_nc(hp + r), hqv = ld_nc(hq + r);
            float f = (seg == 0) ? hpv : (seg == 1) ? hqv : (seg == 2) ? (hpv - hqv) : (hpv * hqv);
            acc0 += W[d] * f;
            acc1 += W[3072 + d] * f;
            acc2 += W[6144 + d] * f;
        }
#pragma unroll
        for (int o = 32; o; o >>= 1) {
            acc0 += __shfl_xor(acc0, o, 64);
            acc1 += __shfl_xor(acc1, o, 64);
            acc2 += __shfl_xor(acc2, o, 64);
        }
        if ((t & 63) == 0) { red[0][t >> 6] = acc0; red[1][t >> 6] = acc1; red[2][t >> 6] = acc2; }
        __syncthreads();
        if (t < 3) {
            float S = red[t][0] + red[t][1] + red[t][2] + red[t][3] + bias[t];
            out[t] = S;
        }
    }
}

extern "C" void kernel_launch(void* const* d_in, const int* in_sizes, int n_in,
                              void* d_out, int out_size, void* d_ws, size_t ws_size,
                              hipStream_t stream) {
    const float* X = (const float*)d_in[0];   // hypo_embeddings [384,768] fp32
    const float* Y = (const float*)d_in[1];   // hyper_embeddings [384,768] fp32
    const float* W = (const float*)d_in[2];   // W_cls [3,3072] fp32
    const float* B = (const float*)d_in[3];   // b_cls [3] fp32
    float* out = (float*)d_out;               // fp32 output

    float* ws = (float*)d_ws;
    float* att       = ws;                  // 147456
    float* attT      = att + NN * NN;       // 147456
    float* rowM      = attT + NN * NN;      // 384
    float* rowRS     = rowM + NN;
    float* colM      = rowRS + NN;
    float* colRS     = colM + NN;
    float* hyper_typ = colRS + NN;
    float* hypo_typ  = hyper_typ + NN;
    float* w_hyper   = hypo_typ + NN;
    float* w_hypo    = w_hyper + NN;
    float* hp        = w_hypo + NN;         // 768
    float* hq        = hp + HH;             // 768
    unsigned* bar    = (unsigned*)(hq + HH); // 256 u32 (4 barriers x 64 u32)

    k_att<<<dim3(48, 48), 256, 0, stream>>>(X, Y, att, attT, bar);
    k_tail<<<128, 256, 0, stream>>>(att, attT, X, Y, W, B,
                                    rowM, rowRS, colM, colRS,
                                    hyper_typ, hypo_typ, w_hyper, w_hypo,
                                    hp, hq, bar, out);
}